// Round 5
// baseline (156.848 us; speedup 1.0000x reference)
//
#include <hip/hip_runtime.h>

// SparseConv3D gather, v5 — branchless 64-rows-per-wave main kernel.
//   k0 sp3d_prep : tbl=-1 fill; sp f32->bf16 (spb, + zero row at index N);
//                  W -> frag-major bf16 wb[tap][frag][lane][8]
//   k1 sp3d_build: tbl[o][out_idx] = in_idx (plain stores; out_idx unique per offset)
//   k2 sp3d_main : 64-thread (1-wave) blocks; wave owns 64 rows x 64 couts (4 row-groups).
//                  Center tap first (dense A), then 26 offsets with ZERO branches in the body:
//                  idx loads (L1-broadcast), index-clamped gathers (invalid -> zero row N),
//                  unconditional B loads + 32 MFMAs per tap. One giant BB -> compiler
//                  software-pipelines loads across taps. No LDS, no barriers, no atomics.
// Workspace: spb[(N+1)*64 bf16] | wb[27*4096 bf16] | tbl[26*N int]  (~23.6 MB)

typedef __bf16 bf16x8 __attribute__((ext_vector_type(8)));
typedef float f32x4 __attribute__((ext_vector_type(4)));

__device__ __forceinline__ unsigned short f2bf(float f) {
    union { float f; unsigned int u; } v; v.f = f;
    unsigned int u = v.u;
    return (unsigned short)((u + 0x7FFFu + ((u >> 16) & 1u)) >> 16);  // RNE
}

__device__ __forceinline__ ushort4 cvt4(float4 v) {
    ushort4 b;
    b.x = f2bf(v.x); b.y = f2bf(v.y); b.z = f2bf(v.z); b.w = f2bf(v.w);
    return b;
}

// ---- k0: fill tbl=-1, sp->bf16 (+zero row), weights -> frag-major bf16 ----
__global__ __launch_bounds__(256) void sp3d_prep(
    const float* __restrict__ sp, const float* __restrict__ w,
    unsigned short* __restrict__ spb, unsigned short* __restrict__ wb,
    int* __restrict__ tbl, int n_rows)
{
    const long gt = (long)blockIdx.x * 256 + threadIdx.x;
    const long stride = (long)gridDim.x * 256;

    const long ntbl = 26L * n_rows;
    for (long i = gt; i < (ntbl >> 2); i += stride)
        *(int4*)&tbl[i * 4] = make_int4(-1, -1, -1, -1);
    if (gt < (ntbl & 3)) tbl[(ntbl & ~3L) + gt] = -1;

    const long nsp = (long)n_rows * 16;  // float4 chunks
    for (long i = gt; i < nsp; i += stride) {
        float4 v = *(const float4*)&sp[i * 4];
        *(ushort4*)&spb[i * 4] = cvt4(v);
    }
    // zero row at index n_rows (gather target for invalid/tail lanes)
    if (gt < 16) {
        ushort4 z; z.x = 0; z.y = 0; z.z = 0; z.w = 0;
        *(ushort4*)&spb[(long)n_rows * 64 + gt * 4] = z;
    }

    // wb chunk c (bf16x8): c = tap*512 + frag*64 + lane; frag = nt*2+half
    // value[j] = W[cout=nt*16+ml][cin=half*32+quad*8+j], w layout [cout][27][cin]
    for (long i = gt; i < 27 * 512; i += stride) {
        int tap = (int)(i >> 9);
        int rem = (int)(i & 511);
        int fragid = rem >> 6, lane = rem & 63;
        int nt = fragid >> 1, half = fragid & 1, ml = lane & 15, quad = lane >> 4;
        const float* src = w + (nt * 16 + ml) * 1728 + tap * 64 + half * 32 + quad * 8;
        float4 v0 = *(const float4*)src;
        float4 v1 = *(const float4*)(src + 4);
        *(ushort4*)&wb[i * 8]     = cvt4(v0);
        *(ushort4*)&wb[i * 8 + 4] = cvt4(v1);
    }
}

// ---- k1: scatter-build neighbor table (no conflicts within an offset) ----
__global__ __launch_bounds__(256) void sp3d_build(
    const int* __restrict__ nei, const int* __restrict__ sizes,
    int* __restrict__ tbl, int n_rows, int P)
{
    const int o = blockIdx.y;
    const int p = blockIdx.x * 256 + threadIdx.x;
    if (p < sizes[o]) {
        int2 pr = *(const int2*)&nei[(o * P + p) * 2];   // (out_idx, in_idx)
        tbl[(long)o * n_rows + pr.x] = pr.y;
    }
}

// ---- k2: branchless gather GEMM; 1 wave = 64 rows x 64 couts ----
__global__ __launch_bounds__(64) void sp3d_main(
    const unsigned short* __restrict__ spb, const unsigned short* __restrict__ wb,
    const float* __restrict__ bias, const int* __restrict__ tbl,
    float* __restrict__ out, int n_rows)
{
    const int lane = threadIdx.x;
    const int ml = lane & 15, quad = lane >> 4;
    const int row0 = blockIdx.x * 64;

    f32x4 acc[4][4];  // [row-group][nt]
    #pragma unroll
    for (int g = 0; g < 4; ++g)
        #pragma unroll
        for (int nt = 0; nt < 4; ++nt) acc[g][nt] = f32x4{0.f, 0.f, 0.f, 0.f};

    // ---- center tap (13): dense A rows, tail rows -> zero row ----
    {
        bf16x8 b[8];
        #pragma unroll
        for (int j = 0; j < 8; ++j)
            b[j] = *(const bf16x8*)(wb + 13 * 4096 + j * 512 + lane * 8);
        #pragma unroll
        for (int g = 0; g < 4; ++g) {
            int r = row0 + g * 16 + ml;
            int rc = (r < n_rows) ? r : n_rows;          // zero row for tail
            const unsigned short* ap = spb + (long)rc * 64 + quad * 8;
            bf16x8 a0 = *(const bf16x8*)ap;
            bf16x8 a1 = *(const bf16x8*)(ap + 32);
            #pragma unroll
            for (int nt = 0; nt < 4; ++nt) {
                acc[g][nt] = __builtin_amdgcn_mfma_f32_16x16x32_bf16(a0, b[nt * 2 + 0], acc[g][nt], 0, 0, 0);
                acc[g][nt] = __builtin_amdgcn_mfma_f32_16x16x32_bf16(a1, b[nt * 2 + 1], acc[g][nt], 0, 0, 0);
            }
        }
    }

    // ---- 26 offsets, fully unrolled, ZERO branches in the body ----
    #pragma unroll
    for (int o = 0; o < 26; ++o) {
        const int tap = o + (o >= 13 ? 1 : 0);

        // neighbor idx per row-group (same addr across quads -> L1 broadcast)
        int v[4];
        #pragma unroll
        for (int g = 0; g < 4; ++g) {
            int r = row0 + g * 16 + ml;
            int rc = (r < n_rows) ? r : n_rows - 1;      // clamp tbl read
            v[g] = tbl[(long)o * n_rows + rc];
        }

        // unconditional B loads (shared by 4 row-groups)
        bf16x8 b[8];
        #pragma unroll
        for (int j = 0; j < 8; ++j)
            b[j] = *(const bf16x8*)(wb + tap * 4096 + j * 512 + lane * 8);

        // index-clamped gathers: invalid lanes read the zero row (index n_rows)
        bf16x8 a0[4], a1[4];
        #pragma unroll
        for (int g = 0; g < 4; ++g) {
            int idx = (v[g] >= 0) ? v[g] : n_rows;       // one cndmask, no data zeroing
            const unsigned short* ap = spb + (long)idx * 64 + quad * 8;
            a0[g] = *(const bf16x8*)ap;
            a1[g] = *(const bf16x8*)(ap + 32);
        }

        #pragma unroll
        for (int g = 0; g < 4; ++g) {
            #pragma unroll
            for (int nt = 0; nt < 4; ++nt) {
                acc[g][nt] = __builtin_amdgcn_mfma_f32_16x16x32_bf16(a0[g], b[nt * 2 + 0], acc[g][nt], 0, 0, 0);
                acc[g][nt] = __builtin_amdgcn_mfma_f32_16x16x32_bf16(a1[g], b[nt * 2 + 1], acc[g][nt], 0, 0, 0);
            }
        }
    }

    // ---- epilogue: bias + one plain store per element (C/D: col=lane&15, row=quad*4+rg) ----
    #pragma unroll
    for (int nt = 0; nt < 4; ++nt) {
        int col = nt * 16 + ml;
        float bv = bias[col];
        #pragma unroll
        for (int g = 0; g < 4; ++g) {
            #pragma unroll
            for (int rg = 0; rg < 4; ++rg) {
                int row = row0 + g * 16 + quad * 4 + rg;
                if (row < n_rows) out[(long)row * 64 + col] = acc[g][nt][rg] + bv;
            }
        }
    }
}

extern "C" void kernel_launch(void* const* d_in, const int* in_sizes, int n_in,
                              void* d_out, int out_size, void* d_ws, size_t ws_size,
                              hipStream_t stream) {
    const float* sp    = (const float*)d_in[0];
    const float* w     = (const float*)d_in[1];
    const float* bias  = (const float*)d_in[2];
    const int*   nei   = (const int*)d_in[3];
    const int*   sizes = (const int*)d_in[4];
    float* out = (float*)d_out;

    const int N = in_sizes[0] / 64;
    const int P = in_sizes[3] / (26 * 2);

    // workspace carve-out (256B aligned): spb (N+1 rows) | wb | tbl
    char* ws = (char*)d_ws;
    unsigned short* spb = (unsigned short*)ws;
    size_t off = ((size_t)(N + 1) * 64 * 2 + 255) & ~(size_t)255;
    unsigned short* wb = (unsigned short*)(ws + off);
    off = (off + 27 * 4096 * 2 + 255) & ~(size_t)255;
    int* tbl = (int*)(ws + off);

    sp3d_prep<<<dim3(2048), 256, 0, stream>>>(sp, w, spb, wb, tbl, N);
    sp3d_build<<<dim3((P + 255) / 256, 26), 256, 0, stream>>>(nei, sizes, tbl, N, P);
    sp3d_main<<<dim3((N + 63) / 64), 64, 0, stream>>>(spb, wb, bias, tbl, out, N);
}

// Round 7
// 149.847 us; speedup vs baseline: 1.0467x; 1.0467x over previous
//
#include <hip/hip_runtime.h>

// SparseConv3D gather, v7 — chain-broken, barrier-free, deep-prefetch main kernel.
//   k0 sp3d_prep : tbl=-1 fill; sp f32->bf16 (spb, + zero row at index N);
//                  W -> frag-major bf16 wb[tap][frag][lane][8]
//   k1 sp3d_build: tbl[o][out_idx] = in_idx (plain stores; out_idx unique per offset)
//   k2 sp3d_main : 256 thr = 4 waves; wave = 16 rows x 64 couts. ALL 26 neighbor
//                  indices preloaded to VGPRs, depth-3 A-gather ring, depth-1 B
//                  double-buffer, per-tap sched_group_barrier {VMEM}{MFMA} pins
//                  (literal args; loop split into static segments).
//                  No LDS, no barriers, no atomics.
// Workspace: spb[(N+1)*64 bf16] | wb[27*4096 bf16] | tbl[26*N int]  (~23.6 MB)

typedef __bf16 bf16x8 __attribute__((ext_vector_type(8)));
typedef float f32x4 __attribute__((ext_vector_type(4)));

__device__ __forceinline__ unsigned short f2bf(float f) {
    union { float f; unsigned int u; } v; v.f = f;
    unsigned int u = v.u;
    return (unsigned short)((u + 0x7FFFu + ((u >> 16) & 1u)) >> 16);  // RNE
}

__device__ __forceinline__ ushort4 cvt4(float4 v) {
    ushort4 b;
    b.x = f2bf(v.x); b.y = f2bf(v.y); b.z = f2bf(v.z); b.w = f2bf(v.w);
    return b;
}

// ---- k0: fill tbl=-1, sp->bf16 (+zero row), weights -> frag-major bf16 ----
__global__ __launch_bounds__(256) void sp3d_prep(
    const float* __restrict__ sp, const float* __restrict__ w,
    unsigned short* __restrict__ spb, unsigned short* __restrict__ wb,
    int* __restrict__ tbl, int n_rows)
{
    const long gt = (long)blockIdx.x * 256 + threadIdx.x;
    const long stride = (long)gridDim.x * 256;

    const long ntbl = 26L * n_rows;
    for (long i = gt; i < (ntbl >> 2); i += stride)
        *(int4*)&tbl[i * 4] = make_int4(-1, -1, -1, -1);
    if (gt < (ntbl & 3)) tbl[(ntbl & ~3L) + gt] = -1;

    const long nsp = (long)n_rows * 16;  // float4 chunks
    for (long i = gt; i < nsp; i += stride) {
        float4 v = *(const float4*)&sp[i * 4];
        *(ushort4*)&spb[i * 4] = cvt4(v);
    }
    // zero row at index n_rows (gather target for invalid/tail lanes)
    if (gt < 16) {
        ushort4 z; z.x = 0; z.y = 0; z.z = 0; z.w = 0;
        *(ushort4*)&spb[(long)n_rows * 64 + gt * 4] = z;
    }

    // wb chunk c (bf16x8): c = tap*512 + frag*64 + lane; frag = nt*2+half
    // value[j] = W[cout=nt*16+ml][cin=half*32+quad*8+j], w layout [cout][27][cin]
    for (long i = gt; i < 27 * 512; i += stride) {
        int tap = (int)(i >> 9);
        int rem = (int)(i & 511);
        int fragid = rem >> 6, lane = rem & 63;
        int nt = fragid >> 1, half = fragid & 1, ml = lane & 15, quad = lane >> 4;
        const float* src = w + (nt * 16 + ml) * 1728 + tap * 64 + half * 32 + quad * 8;
        float4 v0 = *(const float4*)src;
        float4 v1 = *(const float4*)(src + 4);
        *(ushort4*)&wb[i * 8]     = cvt4(v0);
        *(ushort4*)&wb[i * 8 + 4] = cvt4(v1);
    }
}

// ---- k1: scatter-build neighbor table (no conflicts within an offset) ----
__global__ __launch_bounds__(256) void sp3d_build(
    const int* __restrict__ nei, const int* __restrict__ sizes,
    int* __restrict__ tbl, int n_rows, int P)
{
    const int o = blockIdx.y;
    const int p = blockIdx.x * 256 + threadIdx.x;
    if (p < sizes[o]) {
        int2 pr = *(const int2*)&nei[(o * P + p) * 2];   // (out_idx, in_idx)
        tbl[(long)o * n_rows + pr.x] = pr.y;
    }
}

// ---- k2: barrier-free gather GEMM; wave = 16 rows x 64 couts ----
__global__ __launch_bounds__(256, 3) void sp3d_main(
    const unsigned short* __restrict__ spb, const unsigned short* __restrict__ wb,
    const float* __restrict__ bias, const int* __restrict__ tbl,
    float* __restrict__ out, int n_rows)
{
    const int t = threadIdx.x;
    const int wid = t >> 6, lane = t & 63, ml = lane & 15, quad = lane >> 4;
    const int row0 = blockIdx.x * 64;
    const int mrow = row0 + wid * 16 + ml;
    const bool rowok = mrow < n_rows;
    const int mclamp = rowok ? mrow : n_rows - 1;

    // ---- preload ALL neighbor indices to VGPRs (26 independent loads, one wait) ----
    int idxs[26];
    #pragma unroll
    for (int o = 0; o < 26; ++o) idxs[o] = tbl[(long)o * n_rows + mclamp];
    #pragma unroll
    for (int o = 0; o < 26; ++o) idxs[o] = (rowok && idxs[o] >= 0) ? idxs[o] : n_rows;
    const int cidx = rowok ? mrow : n_rows;   // center tap index (zero row for tail)

    // tap -> gather row (tn becomes compile-time under full unroll)
    #define TAPIDX(tn) ((tn) == 13 ? cidx : idxs[(tn) - ((tn) > 13 ? 1 : 0)])

    f32x4 acc[4];
    #pragma unroll
    for (int nt = 0; nt < 4; ++nt) acc[nt] = f32x4{0.f, 0.f, 0.f, 0.f};

    // ---- depth-3 A-prefetch ring + B for tap 0 ----
    bf16x8 pa0[3], pa1[3];
    #pragma unroll
    for (int s = 0; s < 3; ++s) {
        const unsigned short* ap = spb + (long)TAPIDX(s) * 64 + quad * 8;
        pa0[s] = *(const bf16x8*)ap;
        pa1[s] = *(const bf16x8*)(ap + 32);
    }
    bf16x8 b[8];
    #pragma unroll
    for (int j = 0; j < 8; ++j)
        b[j] = *(const bf16x8*)(wb + j * 512 + lane * 8);

    // ---- segment 1: taps 0..23 — A-prefetch(+3) + B-prefetch(+1) + 8 MFMA ----
    #pragma unroll
    for (int tp = 0; tp < 24; ++tp) {
        const bf16x8 ca0 = pa0[tp % 3];
        const bf16x8 ca1 = pa1[tp % 3];

        // A prefetch for tap tp+3 into the vacated ring slot (2 VMEM)
        {
            const unsigned short* ap = spb + (long)TAPIDX(tp + 3) * 64 + quad * 8;
            pa0[tp % 3] = *(const bf16x8*)ap;
            pa1[tp % 3] = *(const bf16x8*)(ap + 32);
        }
        // B prefetch for tap tp+1 (8 VMEM, L1/L2-hot)
        bf16x8 nb[8];
        #pragma unroll
        for (int j = 0; j < 8; ++j)
            nb[j] = *(const bf16x8*)(wb + (tp + 1) * 4096 + j * 512 + lane * 8);

        #pragma unroll
        for (int nt = 0; nt < 4; ++nt) {
            acc[nt] = __builtin_amdgcn_mfma_f32_16x16x32_bf16(ca0, b[nt * 2 + 0], acc[nt], 0, 0, 0);
            acc[nt] = __builtin_amdgcn_mfma_f32_16x16x32_bf16(ca1, b[nt * 2 + 1], acc[nt], 0, 0, 0);
        }
        #pragma unroll
        for (int j = 0; j < 8; ++j) b[j] = nb[j];

        __builtin_amdgcn_sched_group_barrier(0x20, 10, 0);  // VMEM_READ x10
        __builtin_amdgcn_sched_group_barrier(0x8, 8, 0);    // MFMA x8
    }

    // ---- segment 2: taps 24..25 — B-prefetch only ----
    #pragma unroll
    for (int tp = 24; tp < 26; ++tp) {
        const bf16x8 ca0 = pa0[tp % 3];
        const bf16x8 ca1 = pa1[tp % 3];

        bf16x8 nb[8];
        #pragma unroll
        for (int j = 0; j < 8; ++j)
            nb[j] = *(const bf16x8*)(wb + (tp + 1) * 4096 + j * 512 + lane * 8);

        #pragma unroll
        for (int nt = 0; nt < 4; ++nt) {
            acc[nt] = __builtin_amdgcn_mfma_f32_16x16x32_bf16(ca0, b[nt * 2 + 0], acc[nt], 0, 0, 0);
            acc[nt] = __builtin_amdgcn_mfma_f32_16x16x32_bf16(ca1, b[nt * 2 + 1], acc[nt], 0, 0, 0);
        }
        #pragma unroll
        for (int j = 0; j < 8; ++j) b[j] = nb[j];

        __builtin_amdgcn_sched_group_barrier(0x20, 8, 0);   // VMEM_READ x8
        __builtin_amdgcn_sched_group_barrier(0x8, 8, 0);    // MFMA x8
    }

    // ---- segment 3: tap 26 — compute only ----
    {
        const bf16x8 ca0 = pa0[26 % 3];
        const bf16x8 ca1 = pa1[26 % 3];
        #pragma unroll
        for (int nt = 0; nt < 4; ++nt) {
            acc[nt] = __builtin_amdgcn_mfma_f32_16x16x32_bf16(ca0, b[nt * 2 + 0], acc[nt], 0, 0, 0);
            acc[nt] = __builtin_amdgcn_mfma_f32_16x16x32_bf16(ca1, b[nt * 2 + 1], acc[nt], 0, 0, 0);
        }
        __builtin_amdgcn_sched_group_barrier(0x8, 8, 0);    // MFMA x8
    }
    #undef TAPIDX

    // ---- epilogue: bias + one plain store per element ----
    #pragma unroll
    for (int nt = 0; nt < 4; ++nt) {
        int col = nt * 16 + ml;
        float bv = bias[col];
        #pragma unroll
        for (int rg = 0; rg < 4; ++rg) {
            int row = row0 + wid * 16 + quad * 4 + rg;
            if (row < n_rows) out[(long)row * 64 + col] = acc[nt][rg] + bv;
        }
    }
}

extern "C" void kernel_launch(void* const* d_in, const int* in_sizes, int n_in,
                              void* d_out, int out_size, void* d_ws, size_t ws_size,
                              hipStream_t stream) {
    const float* sp    = (const float*)d_in[0];
    const float* w     = (const float*)d_in[1];
    const float* bias  = (const float*)d_in[2];
    const int*   nei   = (const int*)d_in[3];
    const int*   sizes = (const int*)d_in[4];
    float* out = (float*)d_out;

    const int N = in_sizes[0] / 64;
    const int P = in_sizes[3] / (26 * 2);

    // workspace carve-out (256B aligned): spb (N+1 rows) | wb | tbl
    char* ws = (char*)d_ws;
    unsigned short* spb = (unsigned short*)ws;
    size_t off = ((size_t)(N + 1) * 64 * 2 + 255) & ~(size_t)255;
    unsigned short* wb = (unsigned short*)(ws + off);
    off = (off + 27 * 4096 * 2 + 255) & ~(size_t)255;
    int* tbl = (int*)(ws + off);

    sp3d_prep<<<dim3(2048), 256, 0, stream>>>(sp, w, spb, wb, tbl, N);
    sp3d_build<<<dim3((P + 255) / 256, 26), 256, 0, stream>>>(nei, sizes, tbl, N, P);
    sp3d_main<<<dim3((N + 63) / 64), 256, 0, stream>>>(spb, wb, bias, tbl, out, N);
}

// Round 8
// 148.625 us; speedup vs baseline: 1.0553x; 1.0082x over previous
//
#include <hip/hip_runtime.h>

// SparseConv3D gather, v8 — inline-asm pipelined main kernel (HW-guaranteed issue order).
//   k0 sp3d_prep : tbl=n_rows fill; sp f32->bf16 (spb, + zero row at index N);
//                  W -> frag-major bf16 wb[tap][frag][lane][8]
//   k1 sp3d_build: tbl[o][out_idx] = in_idx (plain stores; out_idx unique per offset)
//   k2 sp3d_main : 256 thr = 4 waves; wave = 16 rows x 64 couts. All loads in the
//                  27-tap region are asm volatile global_load_dwordx4 with counted
//                  s_waitcnt vmcnt(N) (issue order guaranteed): per tap issue
//                  B(t+1) x8 + A(t+2) x2, wait vmcnt(12), 8 MFMA. No LDS, no
//                  barriers, no atomics. Compiler loads drained before region.
// Workspace: spb[(N+1)*64 bf16] | wb[27*4096 bf16] | tbl[26*N int]  (~23.6 MB)

typedef __bf16 bf16x8 __attribute__((ext_vector_type(8)));
typedef float f32x4 __attribute__((ext_vector_type(4)));
typedef int   i32x4 __attribute__((ext_vector_type(4)));

__device__ __forceinline__ unsigned short f2bf(float f) {
    union { float f; unsigned int u; } v; v.f = f;
    unsigned int u = v.u;
    return (unsigned short)((u + 0x7FFFu + ((u >> 16) & 1u)) >> 16);  // RNE
}

__device__ __forceinline__ ushort4 cvt4(float4 v) {
    ushort4 b;
    b.x = f2bf(v.x); b.y = f2bf(v.y); b.z = f2bf(v.z); b.w = f2bf(v.w);
    return b;
}

__device__ __forceinline__ bf16x8 asbf(i32x4 v) {
    union { i32x4 i; bf16x8 b; } u; u.i = v; return u.b;
}

// asm 16B load: dst <- mem[sbase + voff + IMM]; issue order preserved (volatile)
#define GLD(dst, voff, sbase, IMM) \
    asm volatile("global_load_dwordx4 %0, %1, %2 offset:" IMM \
                 : "=&v"(dst) : "v"(voff), "s"(sbase))

// ---- k0: fill tbl=n_rows, sp->bf16 (+zero row), weights -> frag-major bf16 ----
__global__ __launch_bounds__(256) void sp3d_prep(
    const float* __restrict__ sp, const float* __restrict__ w,
    unsigned short* __restrict__ spb, unsigned short* __restrict__ wb,
    int* __restrict__ tbl, int n_rows)
{
    const long gt = (long)blockIdx.x * 256 + threadIdx.x;
    const long stride = (long)gridDim.x * 256;

    // tbl = n_rows (zero-row index; build overwrites found entries)
    const long ntbl = 26L * n_rows;
    const int4 fillv = make_int4(n_rows, n_rows, n_rows, n_rows);
    for (long i = gt; i < (ntbl >> 2); i += stride)
        *(int4*)&tbl[i * 4] = fillv;
    if (gt < (ntbl & 3)) tbl[(ntbl & ~3L) + gt] = n_rows;

    const long nsp = (long)n_rows * 16;  // float4 chunks
    for (long i = gt; i < nsp; i += stride) {
        float4 v = *(const float4*)&sp[i * 4];
        *(ushort4*)&spb[i * 4] = cvt4(v);
    }
    // zero row at index n_rows (gather target for invalid/tail lanes)
    if (gt < 16) {
        ushort4 z; z.x = 0; z.y = 0; z.z = 0; z.w = 0;
        *(ushort4*)&spb[(long)n_rows * 64 + gt * 4] = z;
    }

    // wb chunk c (bf16x8): c = tap*512 + frag*64 + lane; frag = nt*2+half
    // value[j] = W[cout=nt*16+ml][cin=half*32+quad*8+j], w layout [cout][27][cin]
    for (long i = gt; i < 27 * 512; i += stride) {
        int tap = (int)(i >> 9);
        int rem = (int)(i & 511);
        int fragid = rem >> 6, lane = rem & 63;
        int nt = fragid >> 1, half = fragid & 1, ml = lane & 15, quad = lane >> 4;
        const float* src = w + (nt * 16 + ml) * 1728 + tap * 64 + half * 32 + quad * 8;
        float4 v0 = *(const float4*)src;
        float4 v1 = *(const float4*)(src + 4);
        *(ushort4*)&wb[i * 8]     = cvt4(v0);
        *(ushort4*)&wb[i * 8 + 4] = cvt4(v1);
    }
}

// ---- k1: scatter-build neighbor table (no conflicts within an offset) ----
__global__ __launch_bounds__(256) void sp3d_build(
    const int* __restrict__ nei, const int* __restrict__ sizes,
    int* __restrict__ tbl, int n_rows, int P)
{
    const int o = blockIdx.y;
    const int p = blockIdx.x * 256 + threadIdx.x;
    if (p < sizes[o]) {
        int2 pr = *(const int2*)&nei[(o * P + p) * 2];   // (out_idx, in_idx)
        tbl[(long)o * n_rows + pr.x] = pr.y;
    }
}

// ---- k2: asm-pipelined gather GEMM; wave = 16 rows x 64 couts ----
__global__ __launch_bounds__(256, 3) void sp3d_main(
    const unsigned short* __restrict__ spb, const unsigned short* __restrict__ wb,
    const float* __restrict__ bias, const int* __restrict__ tbl,
    float* __restrict__ out, int n_rows)
{
    const int t = threadIdx.x;
    const int wid = t >> 6, lane = t & 63, ml = lane & 15, quad = lane >> 4;
    const int row0 = blockIdx.x * 64;
    const int mrow = row0 + wid * 16 + ml;
    const bool rowok = mrow < n_rows;
    const int rc = rowok ? mrow : 0;

    // ---- precompute all 27 A byte-offsets into spb (VGPRs) ----
    int voffA[27];
    #pragma unroll
    for (int o = 0; o < 26; ++o) {
        int tap = o + (o >= 13 ? 1 : 0);
        int idx = tbl[(long)o * n_rows + rc];
        voffA[tap] = ((rowok ? idx : n_rows) << 7) + quad * 16;
    }
    voffA[13] = ((rowok ? mrow : n_rows) << 7) + quad * 16;

    float bv[4];
    #pragma unroll
    for (int nt = 0; nt < 4; ++nt) bv[nt] = bias[nt * 16 + ml];

    f32x4 acc[4];
    #pragma unroll
    for (int nt = 0; nt < 4; ++nt) acc[nt] = f32x4{0.f, 0.f, 0.f, 0.f};

    // drain ALL compiler memory ops: region vmcnt arithmetic must be exact
    asm volatile("s_waitcnt vmcnt(0) lgkmcnt(0)" ::: "memory");
    __builtin_amdgcn_sched_barrier(0);

    const int lb = lane * 16;        // byte offset within a B frag row
    i32x4 B[2][8], A0[3], A1[3];

    // ---- prologue: B(0) x8, A(0) x2, A(1) x2 (order matches steady state) ----
    {
        int vb = lb, vb4 = lb + 4096;
        GLD(B[0][0], vb,  wb, "0");    GLD(B[0][1], vb,  wb, "1024");
        GLD(B[0][2], vb,  wb, "2048"); GLD(B[0][3], vb,  wb, "3072");
        GLD(B[0][4], vb4, wb, "0");    GLD(B[0][5], vb4, wb, "1024");
        GLD(B[0][6], vb4, wb, "2048"); GLD(B[0][7], vb4, wb, "3072");
        GLD(A0[0], voffA[0], spb, "0"); GLD(A1[0], voffA[0], spb, "64");
        GLD(A0[1], voffA[1], spb, "0"); GLD(A1[1], voffA[1], spb, "64");
    }

    // ---- taps 0..24: issue B(t+1) x8 + A(t+2) x2, wait vmcnt(12), 8 MFMA ----
    #pragma unroll
    for (int tp = 0; tp < 25; ++tp) {
        {
            int vb = (tp + 1) * 8192 + lb, vb4 = vb + 4096;
            GLD(B[(tp + 1) & 1][0], vb,  wb, "0");    GLD(B[(tp + 1) & 1][1], vb,  wb, "1024");
            GLD(B[(tp + 1) & 1][2], vb,  wb, "2048"); GLD(B[(tp + 1) & 1][3], vb,  wb, "3072");
            GLD(B[(tp + 1) & 1][4], vb4, wb, "0");    GLD(B[(tp + 1) & 1][5], vb4, wb, "1024");
            GLD(B[(tp + 1) & 1][6], vb4, wb, "2048"); GLD(B[(tp + 1) & 1][7], vb4, wb, "3072");
            GLD(A0[(tp + 2) % 3], voffA[tp + 2], spb, "0");
            GLD(A1[(tp + 2) % 3], voffA[tp + 2], spb, "64");
        }
        // outstanding (worst): A(t)2 B(t)8 A(t+1)2 B(t+1)8 A(t+2)2 = 22; retire through B(t)
        asm volatile("s_waitcnt vmcnt(12)");
        __builtin_amdgcn_sched_barrier(0);
        const bf16x8 a0 = asbf(A0[tp % 3]), a1 = asbf(A1[tp % 3]);
        #pragma unroll
        for (int nt = 0; nt < 4; ++nt) {
            acc[nt] = __builtin_amdgcn_mfma_f32_16x16x32_bf16(a0, asbf(B[tp & 1][nt * 2 + 0]), acc[nt], 0, 0, 0);
            acc[nt] = __builtin_amdgcn_mfma_f32_16x16x32_bf16(a1, asbf(B[tp & 1][nt * 2 + 1]), acc[nt], 0, 0, 0);
        }
    }

    // ---- tap 25: issue B(26) x8 only; wait vmcnt(10) ----
    {
        int vb = 26 * 8192 + lb, vb4 = vb + 4096;
        GLD(B[0][0], vb,  wb, "0");    GLD(B[0][1], vb,  wb, "1024");
        GLD(B[0][2], vb,  wb, "2048"); GLD(B[0][3], vb,  wb, "3072");
        GLD(B[0][4], vb4, wb, "0");    GLD(B[0][5], vb4, wb, "1024");
        GLD(B[0][6], vb4, wb, "2048"); GLD(B[0][7], vb4, wb, "3072");
        asm volatile("s_waitcnt vmcnt(10)");
        __builtin_amdgcn_sched_barrier(0);
        const bf16x8 a0 = asbf(A0[25 % 3]), a1 = asbf(A1[25 % 3]);
        #pragma unroll
        for (int nt = 0; nt < 4; ++nt) {
            acc[nt] = __builtin_amdgcn_mfma_f32_16x16x32_bf16(a0, asbf(B[1][nt * 2 + 0]), acc[nt], 0, 0, 0);
            acc[nt] = __builtin_amdgcn_mfma_f32_16x16x32_bf16(a1, asbf(B[1][nt * 2 + 1]), acc[nt], 0, 0, 0);
        }
    }

    // ---- tap 26: drain, compute ----
    {
        asm volatile("s_waitcnt vmcnt(0)");
        __builtin_amdgcn_sched_barrier(0);
        const bf16x8 a0 = asbf(A0[26 % 3]), a1 = asbf(A1[26 % 3]);
        #pragma unroll
        for (int nt = 0; nt < 4; ++nt) {
            acc[nt] = __builtin_amdgcn_mfma_f32_16x16x32_bf16(a0, asbf(B[0][nt * 2 + 0]), acc[nt], 0, 0, 0);
            acc[nt] = __builtin_amdgcn_mfma_f32_16x16x32_bf16(a1, asbf(B[0][nt * 2 + 1]), acc[nt], 0, 0, 0);
        }
    }

    // ---- epilogue: bias + one plain store per element ----
    #pragma unroll
    for (int nt = 0; nt < 4; ++nt) {
        int col = nt * 16 + ml;
        #pragma unroll
        for (int rg = 0; rg < 4; ++rg) {
            int row = row0 + wid * 16 + quad * 4 + rg;
            if (row < n_rows) out[(long)row * 64 + col] = acc[nt][rg] + bv[nt];
        }
    }
}

extern "C" void kernel_launch(void* const* d_in, const int* in_sizes, int n_in,
                              void* d_out, int out_size, void* d_ws, size_t ws_size,
                              hipStream_t stream) {
    const float* sp    = (const float*)d_in[0];
    const float* w     = (const float*)d_in[1];
    const float* bias  = (const float*)d_in[2];
    const int*   nei   = (const int*)d_in[3];
    const int*   sizes = (const int*)d_in[4];
    float* out = (float*)d_out;

    const int N = in_sizes[0] / 64;
    const int P = in_sizes[3] / (26 * 2);

    // workspace carve-out (256B aligned): spb (N+1 rows) | wb | tbl
    char* ws = (char*)d_ws;
    unsigned short* spb = (unsigned short*)ws;
    size_t off = ((size_t)(N + 1) * 64 * 2 + 255) & ~(size_t)255;
    unsigned short* wb = (unsigned short*)(ws + off);
    off = (off + 27 * 4096 * 2 + 255) & ~(size_t)255;
    int* tbl = (int*)(ws + off);

    sp3d_prep<<<dim3(2048), 256, 0, stream>>>(sp, w, spb, wb, tbl, N);
    sp3d_build<<<dim3((P + 255) / 256, 26), 256, 0, stream>>>(nei, sizes, tbl, N, P);
    sp3d_main<<<dim3((N + 63) / 64), 256, 0, stream>>>(spb, wb, bias, tbl, out, N);
}